// Round 12
// baseline (4819.478 us; speedup 1.0000x reference)
//
#include <hip/hip_runtime.h>
#include <hip/hip_bf16.h>
#include <hip/hip_fp16.h>

#define SS 512
#define BB 64
#define EE 512
#define HH 1024

typedef _Float16 f16x8 __attribute__((ext_vector_type(8)));
typedef _Float16 f16x4 __attribute__((ext_vector_type(4)));
typedef float f32x4 __attribute__((ext_vector_type(4)));
typedef unsigned long long u64;

__device__ __forceinline__ f16x8 ldh8(const _Float16* p) {
    return *reinterpret_cast<const f16x8*>(p);
}

// ---------- prep: [K1+K2][HH] fp32 (wih over whh) -> [HH][K] fp16, coalesced reads ----------
__global__ void prep_wt(const float* __restrict__ wih, const float* __restrict__ whh,
                        int K1, int K, _Float16* __restrict__ out)
{
    int k = blockIdx.x;                // source row (input feature)
    const float* src = (k < K1) ? (wih + (size_t)k * HH) : (whh + (size_t)(k - K1) * HH);
    for (int n = threadIdx.x; n < HH; n += blockDim.x)
        out[(size_t)n * K + k] = (_Float16)src[n];
}

// bias layout: [0]=L0 fwd, [1024]=L1 fwd, [2048]=L0 bwd, [3072]=L1 bwd
__global__ void prep_bias(const float* f0ih, const float* f0hh,
                          const float* f1ih, const float* f1hh,
                          const float* b0ih, const float* b0hh,
                          const float* b1ih, const float* b1hh,
                          float* __restrict__ bias)
{
    int i = threadIdx.x;
    bias[i]          = f0ih[i] + f0hh[i];
    bias[1024 + i]   = f1ih[i] + f1hh[i];
    bias[2048 + i]   = b0ih[i] + b0hh[i];
    bias[3072 + i]   = b1ih[i] + b1hh[i];
}

// ---------- embedding pre-gather: embx[t][b][e] = fp16(emb[x[b][t]][e])  (linear layout) ----------
__global__ void prep_embx(const int* __restrict__ x, const float* __restrict__ emb,
                          _Float16* __restrict__ embx)
{
    int t = blockIdx.x >> 6, b = blockIdx.x & 63;
    const float* src = emb + (size_t)x[b * SS + t] * EE;
    _Float16* dst = embx + ((size_t)t * BB + b) * EE;
    int i = threadIdx.x * 4;            // 128 threads * 4 = 512
    float4 v = *reinterpret_cast<const float4*>(src + i);
    f16x4 h;
    h[0] = (_Float16)v.x; h[1] = (_Float16)v.y;
    h[2] = (_Float16)v.z; h[3] = (_Float16)v.w;
    *reinterpret_cast<f16x4*>(dst + i) = h;
}

// ---------- fragment-tiled h state via agent-scope (L3-coherent) atomics ----------
// half-index(row,col) = (col>>5)*2048 + (row>>4)*512 + ((col>>3)&3)*128 + (row&15)*8 + (col&7)
// slot = 64x1024 halves = 16384 u64; 4 slots deep per buffer.
__device__ __forceinline__ f16x8 ld_tile(const u64* __restrict__ slot, int k0, int m, int kg, int r)
{
    union { u64 u[2]; f16x8 v; } z;
    const u64* p = slot + ((k0 >> 5) * 512 + m * 128 + kg * 32 + r * 2);
    z.u[0] = __hip_atomic_load(p,     __ATOMIC_RELAXED, __HIP_MEMORY_SCOPE_AGENT);
    z.u[1] = __hip_atomic_load(p + 1, __ATOMIC_RELAXED, __HIP_MEMORY_SCOPE_AGENT);
    return z.v;
}

__device__ __forceinline__ void st_tile(u64* __restrict__ slot, int row, int col4, f16x4 hv)
{
    union { u64 u; f16x4 v; } z; z.v = hv;
    u64* p = slot + ((col4 >> 5) * 512 + (row >> 4) * 128 + ((col4 >> 3) & 3) * 32
                     + (row & 15) * 2 + ((col4 >> 2) & 1));
    __hip_atomic_store(p, z.u, __ATOMIC_RELAXED, __HIP_MEMORY_SCOPE_AGENT);
}

// ---------- per-block monotonic flags, one 64B line each: flg[chain][block] ----------
__device__ __forceinline__ void wave_wait(const unsigned* a /*16-line slice base*/, unsigned ta,
                                          const unsigned* b /*64-line base or null*/, unsigned tb)
{
    const int lane = threadIdx.x & 63;
    const unsigned* pa = a + (lane & 15) * 16;
    const unsigned* pb = b ? b + lane * 16 : nullptr;
    for (;;) {
        bool ok = __hip_atomic_load(pa, __ATOMIC_RELAXED, __HIP_MEMORY_SCOPE_AGENT) >= ta;
        if (pb)
            ok &= __hip_atomic_load(pb, __ATOMIC_RELAXED, __HIP_MEMORY_SCOPE_AGENT) >= tb;
        if (__all(ok)) break;
        __builtin_amdgcn_s_sleep(1);
    }
}

// ---------- persistent RNN kernel ----------
// 256 blocks: task = bid>>6 (0:L0f 1:L0b 2:L1f 3:L1b), tile = bid&63 -> 16 output cols.
// R9 verbatim except L1's phase order: consume h0(t) FIRST (L0 runs ahead; its flag is
// already set), THEN wait/load/MFMA h1(t-1) — keeps the h1 recurrence cycle minimal.
__global__ __launch_bounds__(256, 1)
void rnn_persistent(const int* __restrict__ x, const float* __restrict__ emb,
                    const _Float16* __restrict__ embx,          // may be null -> gather in-loop
                    const _Float16* __restrict__ W0f, const _Float16* __restrict__ W1f,
                    const _Float16* __restrict__ W0b, const _Float16* __restrict__ W1b,
                    const float* __restrict__ bias,
                    u64* __restrict__ h0f, u64* __restrict__ h1f,
                    u64* __restrict__ h0b, u64* __restrict__ h1b,
                    float* __restrict__ h1fin, unsigned* __restrict__ flg)
{
    const int bid  = blockIdx.x;
    const int task = bid >> 6;
    const int tile = bid & 63;
    const int dir  = task & 1;
    const bool isL1 = task >= 2;
    const int lane = threadIdx.x & 63;
    const int wave = threadIdx.x >> 6;
    const int r    = lane & 15;       // output col within tile / A row within 16-frag
    const int kg   = lane >> 4;       // k-group (8 halves)
    const int tid  = threadIdx.x;

    __shared__ float red[4][64][20];          // 20,480 B

    // --- weights -> registers (per-wave slices, loaded once from linear [HH][K]) ---
    // B-frag lane(kg,r) = W[(tile*16 + r)*K + k + kg*8 .. +7]
    f16x8 w0e[4], w0h[8], w1a[8], w1b[8];
    if (!isL1) {
        const _Float16* Wrow = (dir ? W0b : W0f) + (size_t)(tile * 16 + r) * 1536;
#pragma unroll
        for (int i = 0; i < 4; ++i)
            w0e[i] = ldh8(Wrow + (wave * 4 + i) * 32 + kg * 8);
#pragma unroll
        for (int i = 0; i < 8; ++i)
            w0h[i] = ldh8(Wrow + EE + wave * 256 + i * 32 + kg * 8);
    } else {
        const _Float16* Wrow = (dir ? W1b : W1f) + (size_t)(tile * 16 + r) * 2048;
#pragma unroll
        for (int i = 0; i < 8; ++i) {
            w1a[i] = ldh8(Wrow + wave * 256 + i * 32 + kg * 8);
            w1b[i] = ldh8(Wrow + HH + wave * 256 + i * 32 + kg * 8);
        }
    }

    u64* hbuf0 = dir ? h0b : h0f;     // layer0 state, 4 slots x 16384 u64
    u64* h1buf = dir ? h1b : h1f;

    unsigned* F_L0 = flg + (size_t)dir * 64 * 16;          // chains: 0,1 = L0 f/b
    unsigned* F_L1 = flg + (size_t)(2 + dir) * 64 * 16;    //         2,3 = L1 f/b
    unsigned* F_own = (isL1 ? F_L1 : F_L0) + tile * 16;
    const unsigned* myslice_L0 = F_L0 + 16 * wave * 16;    // wave's 16 slice producers
    const unsigned* myslice_L1 = F_L1 + 16 * wave * 16;

    for (int t = 0; t < SS; ++t) {
        f32x4 acc[4];
#pragma unroll
        for (int m = 0; m < 4; ++m) acc[m] = (f32x4){0.f, 0.f, 0.f, 0.f};

        if (!isL1) {
            // ===== layer 0, step t : A = [embx(t_eff) | h0(t-1)] =====
            const int t_eff = dir ? (SS - 1 - t) : t;
            // --- emb segment first (independent of recurrence): wave covers [wave*128,+128)
            if (embx) {
                const _Float16* Aemb = embx + (size_t)t_eff * (BB * EE);
#pragma unroll
                for (int i = 0; i < 4; ++i) {
                    const int k = wave * 128 + i * 32;
#pragma unroll
                    for (int m = 0; m < 4; ++m) {
                        f16x8 a = ldh8(Aemb + (m * 16 + r) * EE + k + kg * 8);
                        acc[m] = __builtin_amdgcn_mfma_f32_16x16x32_f16(a, w0e[i], acc[m], 0, 0, 0);
                    }
                }
            } else {
                const float* erow[4];
#pragma unroll
                for (int m = 0; m < 4; ++m)
                    erow[m] = emb + (size_t)x[(m * 16 + r) * SS + t_eff] * EE;
#pragma unroll
                for (int i = 0; i < 4; ++i) {
                    const int k = wave * 128 + i * 32;
#pragma unroll
                    for (int m = 0; m < 4; ++m) {
                        const float* p = erow[m] + k + kg * 8;
                        float4 lo = *reinterpret_cast<const float4*>(p);
                        float4 hi = *reinterpret_cast<const float4*>(p + 4);
                        f16x8 a;
                        a[0] = (_Float16)lo.x; a[1] = (_Float16)lo.y;
                        a[2] = (_Float16)lo.z; a[3] = (_Float16)lo.w;
                        a[4] = (_Float16)hi.x; a[5] = (_Float16)hi.y;
                        a[6] = (_Float16)hi.z; a[7] = (_Float16)hi.w;
                        acc[m] = __builtin_amdgcn_mfma_f32_16x16x32_f16(a, w0e[i], acc[m], 0, 0, 0);
                    }
                }
            }
            // --- wait: my k-slice of h0(t-1) ready (16 producers); slot guard vs L1(t-4)
            if (t >= 1) {
                wave_wait(myslice_L0, (unsigned)t,
                          (t >= 4) ? F_L1 : nullptr, (unsigned)(t - 3));
                const u64* hprev = hbuf0 + (size_t)((t - 1) & 3) * 16384;
#pragma unroll
                for (int i = 0; i < 8; ++i) {
                    const int k = wave * 256 + i * 32;
#pragma unroll
                    for (int m = 0; m < 4; ++m) {
                        f16x8 a = ld_tile(hprev, k, m, kg, r);
                        acc[m] = __builtin_amdgcn_mfma_f32_16x16x32_f16(a, w0h[i], acc[m], 0, 0, 0);
                    }
                }
            }
        } else {
            // ===== layer 1, step t : A = [h0(t) | h1(t-1)] =====
            // --- phase A: h0(t). L0 runs ahead (guard lets it lead by up to 3), so this
            //     flag is normally already set; h0 load+MFMA runs OUTSIDE the h1 cycle.
            wave_wait(myslice_L0, (unsigned)(t + 1), nullptr, 0u);
            const u64* h0cur = hbuf0 + (size_t)(t & 3) * 16384;
#pragma unroll
            for (int i = 0; i < 8; ++i) {
                const int k = wave * 256 + i * 32;
#pragma unroll
                for (int m = 0; m < 4; ++m) {
                    f16x8 a = ld_tile(h0cur, k, m, kg, r);
                    acc[m] = __builtin_amdgcn_mfma_f32_16x16x32_f16(a, w1a[i], acc[m], 0, 0, 0);
                }
            }
            // --- phase B: h1(t-1) — the tight recurrence; keep its observe->publish minimal
            if (t >= 1) {
                wave_wait(myslice_L1, (unsigned)t, nullptr, 0u);
                const u64* h1prev = h1buf + (size_t)((t - 1) & 3) * 16384;
#pragma unroll
                for (int i = 0; i < 8; ++i) {
                    const int k = wave * 256 + i * 32;
#pragma unroll
                    for (int m = 0; m < 4; ++m) {
                        f16x8 a = ld_tile(h1prev, k, m, kg, r);
                        acc[m] = __builtin_amdgcn_mfma_f32_16x16x32_f16(a, w1b[i], acc[m], 0, 0, 0);
                    }
                }
            }
        }

        // ---------- cross-wave reduce + epilogue ----------
#pragma unroll
        for (int m = 0; m < 4; ++m)
#pragma unroll
            for (int rr = 0; rr < 4; ++rr)
                red[wave][m * 16 + kg * 4 + rr][r] = acc[m][rr];
        __syncthreads();
        {
            const int row = tid >> 2;          // 0..63
            const int c   = (tid & 3) * 4;     // 0,4,8,12
            f32x4 s = *reinterpret_cast<f32x4*>(&red[0][row][c]);
#pragma unroll
            for (int w = 1; w < 4; ++w) s += *reinterpret_cast<f32x4*>(&red[w][row][c]);
            const int nb = tile * 16 + c;
            const float* bp = bias + (isL1 ? 1024 : 0) + (dir ? 2048 : 0) + nb;
            float4 bv = *reinterpret_cast<const float4*>(bp);
            float v0 = tanhf(s[0] + bv.x), v1 = tanhf(s[1] + bv.y);
            float v2 = tanhf(s[2] + bv.z), v3 = tanhf(s[3] + bv.w);
            f16x4 hv; hv[0] = (_Float16)v0; hv[1] = (_Float16)v1;
            hv[2] = (_Float16)v2; hv[3] = (_Float16)v3;
            u64* hout = (isL1 ? h1buf : hbuf0) + (size_t)(t & 3) * 16384;
            st_tile(hout, row, nb, hv);
            if (isL1 && t == SS - 1) {
                float4 fv; fv.x = v0; fv.y = v1; fv.z = v2; fv.w = v3;
                *reinterpret_cast<float4*>(h1fin + (size_t)dir * (BB * HH) + row * HH + nb) = fv;
            }
        }
        // ---------- publish: drain all waves' sc1 stores, then flag = t+1 (plain store)
        __syncthreads();
        if (tid == 0)
            __hip_atomic_store(F_own, (unsigned)(t + 1), __ATOMIC_RELAXED,
                               __HIP_MEMORY_SCOPE_AGENT);
    }
}

// ---------- FC head (all fp32, runs once) ----------
__global__ void fc1_kernel(const float* __restrict__ h1fin, const float* __restrict__ w,
                           const float* __restrict__ b, float* __restrict__ v)
{
    int idx = blockIdx.x * 256 + threadIdx.x;   // (batch, out-feature)
    int bb = idx >> 6, nn = idx & 63;
    const float* hf = h1fin + bb * HH;
    const float* hb = h1fin + BB * HH + bb * HH;
    float s = b[nn];
#pragma unroll 8
    for (int k = 0; k < HH; ++k) s += hf[k] * w[k * 64 + nn];
#pragma unroll 8
    for (int k = 0; k < HH; ++k) s += hb[k] * w[(HH + k) * 64 + nn];
    v[idx] = s;
}

__global__ void fc2_kernel(const float* __restrict__ v, const float* __restrict__ w,
                           const float* __restrict__ b, float* __restrict__ out)
{
    int idx = threadIdx.x;
    if (idx >= BB * 2) return;
    int bb = idx >> 1, c = idx & 1;
    float s = b[c];
    const float* vb = v + bb * 64;
#pragma unroll
    for (int j = 0; j < 64; ++j) s += vb[j] * w[j * 2 + c];
    out[bb * 2 + c] = s;
}

extern "C" void kernel_launch(void* const* d_in, const int* in_sizes, int n_in,
                              void* d_out, int out_size, void* d_ws, size_t ws_size,
                              hipStream_t stream)
{
    const int*   x        = (const int*)  d_in[0];
    const float* emb      = (const float*)d_in[1];
    const float* fw0_wih  = (const float*)d_in[2];
    const float* fw0_bih  = (const float*)d_in[3];
    const float* fw0_whh  = (const float*)d_in[4];
    const float* fw0_bhh  = (const float*)d_in[5];
    const float* fw1_wih  = (const float*)d_in[6];
    const float* fw1_bih  = (const float*)d_in[7];
    const float* fw1_whh  = (const float*)d_in[8];
    const float* fw1_bhh  = (const float*)d_in[9];
    const float* bw0_wih  = (const float*)d_in[10];
    const float* bw0_bih  = (const float*)d_in[11];
    const float* bw0_whh  = (const float*)d_in[12];
    const float* bw0_bhh  = (const float*)d_in[13];
    const float* bw1_wih  = (const float*)d_in[14];
    const float* bw1_bih  = (const float*)d_in[15];
    const float* bw1_whh  = (const float*)d_in[16];
    const float* bw1_bhh  = (const float*)d_in[17];
    const float* fc1_w    = (const float*)d_in[18];
    const float* fc1_b    = (const float*)d_in[19];
    const float* fc2_w    = (const float*)d_in[20];
    const float* fc2_b    = (const float*)d_in[21];

    size_t off = 0;
    char* wsb = (char*)d_ws;
    auto take = [&](size_t bytes) -> void* {
        void* p = wsb + off;
        off += (bytes + 255) & ~(size_t)255;
        return p;
    };
    _Float16* W0f   = (_Float16*)take((size_t)HH * 1536 * 2);
    _Float16* W1f   = (_Float16*)take((size_t)HH * 2048 * 2);
    _Float16* W0b   = (_Float16*)take((size_t)HH * 1536 * 2);
    _Float16* W1b   = (_Float16*)take((size_t)HH * 2048 * 2);
    float*    bias  = (float*)   take(4096 * 4);
    u64*      h0f   = (u64*)     take((size_t)4 * 16384 * 8);
    u64*      h1f   = (u64*)     take((size_t)4 * 16384 * 8);
    u64*      h0b   = (u64*)     take((size_t)4 * 16384 * 8);
    u64*      h1b   = (u64*)     take((size_t)4 * 16384 * 8);
    float*    h1fin = (float*)   take((size_t)2 * BB * HH * 4);
    float*    vmid  = (float*)   take(4096 * 4);
    unsigned* flg   = (unsigned*)take((size_t)4 * 64 * 16 * 4);   // 4 chains x 64 blocks x 64B
    _Float16* embx  = (_Float16*)take((size_t)SS * BB * EE * 2);  // 32 MB
    bool use_embx = (ws_size >= off);

    prep_wt<<<1536, 256, 0, stream>>>(fw0_wih, fw0_whh, EE, 1536, W0f);
    prep_wt<<<2048, 256, 0, stream>>>(fw1_wih, fw1_whh, HH, 2048, W1f);
    prep_wt<<<1536, 256, 0, stream>>>(bw0_wih, bw0_whh, EE, 1536, W0b);
    prep_wt<<<2048, 256, 0, stream>>>(bw1_wih, bw1_whh, HH, 2048, W1b);
    prep_bias<<<1, 1024, 0, stream>>>(fw0_bih, fw0_bhh, fw1_bih, fw1_bhh,
                                      bw0_bih, bw0_bhh, bw1_bih, bw1_bhh, bias);
    if (use_embx)
        prep_embx<<<SS * BB, 128, 0, stream>>>(x, emb, embx);
    hipMemsetAsync(flg, 0, (size_t)4 * 64 * 16 * 4, stream);

    const _Float16* embx_arg = use_embx ? embx : nullptr;
    void* args[] = {(void*)&x, (void*)&emb, (void*)&embx_arg,
                    (void*)&W0f, (void*)&W1f, (void*)&W0b, (void*)&W1b,
                    (void*)&bias, (void*)&h0f, (void*)&h1f, (void*)&h0b, (void*)&h1b,
                    (void*)&h1fin, (void*)&flg};
    hipLaunchCooperativeKernel((void*)rnn_persistent, dim3(256), dim3(256), args, 0, stream);

    fc1_kernel<<<16, 256, 0, stream>>>(h1fin, fc1_w, fc1_b, vmid);
    fc2_kernel<<<1, 128, 0, stream>>>(vmid, fc2_w, fc2_b, (float*)d_out);
}

// Round 14
// 4283.931 us; speedup vs baseline: 1.1250x; 1.1250x over previous
//
#include <hip/hip_runtime.h>
#include <hip/hip_bf16.h>
#include <hip/hip_fp16.h>

#define SS 512
#define BB 64
#define EE 512
#define HH 1024

typedef _Float16 f16x8 __attribute__((ext_vector_type(8)));
typedef _Float16 f16x4 __attribute__((ext_vector_type(4)));
typedef float f32x4 __attribute__((ext_vector_type(4)));
typedef unsigned long long u64;

__device__ __forceinline__ f16x8 ldh8(const _Float16* p) {
    return *reinterpret_cast<const f16x8*>(p);
}

// ---------- prep: [K1+K2][HH] fp32 (wih over whh) -> [HH][K] fp16, coalesced reads ----------
__global__ void prep_wt(const float* __restrict__ wih, const float* __restrict__ whh,
                        int K1, int K, _Float16* __restrict__ out)
{
    int k = blockIdx.x;                // source row (input feature)
    const float* src = (k < K1) ? (wih + (size_t)k * HH) : (whh + (size_t)(k - K1) * HH);
    for (int n = threadIdx.x; n < HH; n += blockDim.x)
        out[(size_t)n * K + k] = (_Float16)src[n];
}

// bias layout: [0]=L0 fwd, [1024]=L1 fwd, [2048]=L0 bwd, [3072]=L1 bwd
__global__ void prep_bias(const float* f0ih, const float* f0hh,
                          const float* f1ih, const float* f1hh,
                          const float* b0ih, const float* b0hh,
                          const float* b1ih, const float* b1hh,
                          float* __restrict__ bias)
{
    int i = threadIdx.x;
    bias[i]          = f0ih[i] + f0hh[i];
    bias[1024 + i]   = f1ih[i] + f1hh[i];
    bias[2048 + i]   = b0ih[i] + b0hh[i];
    bias[3072 + i]   = b1ih[i] + b1hh[i];
}

// ---------- embedding pre-gather: embx[t][b][e] = fp16(emb[x[b][t]][e])  (linear layout) ----------
__global__ void prep_embx(const int* __restrict__ x, const float* __restrict__ emb,
                          _Float16* __restrict__ embx)
{
    int t = blockIdx.x >> 6, b = blockIdx.x & 63;
    const float* src = emb + (size_t)x[b * SS + t] * EE;
    _Float16* dst = embx + ((size_t)t * BB + b) * EE;
    int i = threadIdx.x * 4;            // 128 threads * 4 = 512
    float4 v = *reinterpret_cast<const float4*>(src + i);
    f16x4 h;
    h[0] = (_Float16)v.x; h[1] = (_Float16)v.y;
    h[2] = (_Float16)v.z; h[3] = (_Float16)v.w;
    *reinterpret_cast<f16x4*>(dst + i) = h;
}

// ---------- fragment-tiled h state via agent-scope (L3-coherent) atomics ----------
// half-index(row,col) = (col>>5)*2048 + (row>>4)*512 + ((col>>3)&3)*128 + (row&15)*8 + (col&7)
// slot = 64x1024 halves = 16384 u64; 4 slots deep per buffer.
__device__ __forceinline__ f16x8 ld_tile(const u64* __restrict__ slot, int k0, int m, int kg, int r)
{
    union { u64 u[2]; f16x8 v; } z;
    const u64* p = slot + ((k0 >> 5) * 512 + m * 128 + kg * 32 + r * 2);
    z.u[0] = __hip_atomic_load(p,     __ATOMIC_RELAXED, __HIP_MEMORY_SCOPE_AGENT);
    z.u[1] = __hip_atomic_load(p + 1, __ATOMIC_RELAXED, __HIP_MEMORY_SCOPE_AGENT);
    return z.v;
}

__device__ __forceinline__ void st_tile(u64* __restrict__ slot, int row, int col4, f16x4 hv)
{
    union { u64 u; f16x4 v; } z; z.v = hv;
    u64* p = slot + ((col4 >> 5) * 512 + (row >> 4) * 128 + ((col4 >> 3) & 3) * 32
                     + (row & 15) * 2 + ((col4 >> 2) & 1));
    __hip_atomic_store(p, z.u, __ATOMIC_RELAXED, __HIP_MEMORY_SCOPE_AGENT);
}

// ---------- per-block monotonic flags, one 64B line each: flg[chain][block] ----------
__device__ __forceinline__ void wave_wait(const unsigned* a /*16-line slice base*/, unsigned ta,
                                          const unsigned* b /*64-line base or null*/, unsigned tb)
{
    const int lane = threadIdx.x & 63;
    const unsigned* pa = a + (lane & 15) * 16;
    const unsigned* pb = b ? b + lane * 16 : nullptr;
    for (;;) {
        bool ok = __hip_atomic_load(pa, __ATOMIC_RELAXED, __HIP_MEMORY_SCOPE_AGENT) >= ta;
        if (pb)
            ok &= __hip_atomic_load(pb, __ATOMIC_RELAXED, __HIP_MEMORY_SCOPE_AGENT) >= tb;
        if (__all(ok)) break;
        __builtin_amdgcn_s_sleep(1);
    }
}

// ---------- persistent RNN kernel ----------
// 256 blocks: task = bid>>6 (0:L0f 1:L0b 2:L1f 3:L1b), tile = bid&63 -> 16 output cols.
// Weights in VGPRs (per-wave K-slice, loaded once from linear [HH][K]); LDS holds only
// the cross-wave reduce buffer; dataflow sync via per-block monotonic flags + L3 atomics.
// NOTE (session ledger): this exact structure is the verified optimum. Five variants
// (16B asm loads / batched reg loads / 8-deep slots / 32-col geometry / speculative
// probe-loads) all failed identically (absmax 2.49e-2) — the wait-then-load discipline
// and this topology are load-bearing. Do not perturb without a coherence-probe harness.
__global__ __launch_bounds__(256, 1)
void rnn_persistent(const int* __restrict__ x, const float* __restrict__ emb,
                    const _Float16* __restrict__ embx,          // may be null -> gather in-loop
                    const _Float16* __restrict__ W0f, const _Float16* __restrict__ W1f,
                    const _Float16* __restrict__ W0b, const _Float16* __restrict__ W1b,
                    const float* __restrict__ bias,
                    u64* __restrict__ h0f, u64* __restrict__ h1f,
                    u64* __restrict__ h0b, u64* __restrict__ h1b,
                    float* __restrict__ h1fin, unsigned* __restrict__ flg)
{
    const int bid  = blockIdx.x;
    const int task = bid >> 6;
    const int tile = bid & 63;
    const int dir  = task & 1;
    const bool isL1 = task >= 2;
    const int lane = threadIdx.x & 63;
    const int wave = threadIdx.x >> 6;
    const int r    = lane & 15;       // output col within tile / A row within 16-frag
    const int kg   = lane >> 4;       // k-group (8 halves)
    const int tid  = threadIdx.x;

    __shared__ float red[4][64][20];          // 20,480 B

    // --- weights -> registers (per-wave slices, loaded once from linear [HH][K]) ---
    // B-frag lane(kg,r) = W[(tile*16 + r)*K + k + kg*8 .. +7]
    f16x8 w0e[4], w0h[8], w1a[8], w1b[8];
    if (!isL1) {
        const _Float16* Wrow = (dir ? W0b : W0f) + (size_t)(tile * 16 + r) * 1536;
#pragma unroll
        for (int i = 0; i < 4; ++i)
            w0e[i] = ldh8(Wrow + (wave * 4 + i) * 32 + kg * 8);
#pragma unroll
        for (int i = 0; i < 8; ++i)
            w0h[i] = ldh8(Wrow + EE + wave * 256 + i * 32 + kg * 8);
    } else {
        const _Float16* Wrow = (dir ? W1b : W1f) + (size_t)(tile * 16 + r) * 2048;
#pragma unroll
        for (int i = 0; i < 8; ++i) {
            w1a[i] = ldh8(Wrow + wave * 256 + i * 32 + kg * 8);
            w1b[i] = ldh8(Wrow + HH + wave * 256 + i * 32 + kg * 8);
        }
    }

    u64* hbuf0 = dir ? h0b : h0f;     // layer0 state, 4 slots x 16384 u64
    u64* h1buf = dir ? h1b : h1f;

    unsigned* F_L0 = flg + (size_t)dir * 64 * 16;          // chains: 0,1 = L0 f/b
    unsigned* F_L1 = flg + (size_t)(2 + dir) * 64 * 16;    //         2,3 = L1 f/b
    unsigned* F_own = (isL1 ? F_L1 : F_L0) + tile * 16;
    const unsigned* myslice_L0 = F_L0 + 16 * wave * 16;    // wave's 16 slice producers
    const unsigned* myslice_L1 = F_L1 + 16 * wave * 16;

    for (int t = 0; t < SS; ++t) {
        f32x4 acc[4];
#pragma unroll
        for (int m = 0; m < 4; ++m) acc[m] = (f32x4){0.f, 0.f, 0.f, 0.f};

        if (!isL1) {
            // ===== layer 0, step t : A = [embx(t_eff) | h0(t-1)] =====
            const int t_eff = dir ? (SS - 1 - t) : t;
            // --- emb segment first (independent of recurrence): wave covers [wave*128,+128)
            if (embx) {
                const _Float16* Aemb = embx + (size_t)t_eff * (BB * EE);
#pragma unroll
                for (int i = 0; i < 4; ++i) {
                    const int k = wave * 128 + i * 32;
#pragma unroll
                    for (int m = 0; m < 4; ++m) {
                        f16x8 a = ldh8(Aemb + (m * 16 + r) * EE + k + kg * 8);
                        acc[m] = __builtin_amdgcn_mfma_f32_16x16x32_f16(a, w0e[i], acc[m], 0, 0, 0);
                    }
                }
            } else {
                const float* erow[4];
#pragma unroll
                for (int m = 0; m < 4; ++m)
                    erow[m] = emb + (size_t)x[(m * 16 + r) * SS + t_eff] * EE;
#pragma unroll
                for (int i = 0; i < 4; ++i) {
                    const int k = wave * 128 + i * 32;
#pragma unroll
                    for (int m = 0; m < 4; ++m) {
                        const float* p = erow[m] + k + kg * 8;
                        float4 lo = *reinterpret_cast<const float4*>(p);
                        float4 hi = *reinterpret_cast<const float4*>(p + 4);
                        f16x8 a;
                        a[0] = (_Float16)lo.x; a[1] = (_Float16)lo.y;
                        a[2] = (_Float16)lo.z; a[3] = (_Float16)lo.w;
                        a[4] = (_Float16)hi.x; a[5] = (_Float16)hi.y;
                        a[6] = (_Float16)hi.z; a[7] = (_Float16)hi.w;
                        acc[m] = __builtin_amdgcn_mfma_f32_16x16x32_f16(a, w0e[i], acc[m], 0, 0, 0);
                    }
                }
            }
            // --- wait: my k-slice of h0(t-1) ready (16 producers); slot guard vs L1(t-4)
            if (t >= 1) {
                wave_wait(myslice_L0, (unsigned)t,
                          (t >= 4) ? F_L1 : nullptr, (unsigned)(t - 3));
                const u64* hprev = hbuf0 + (size_t)((t - 1) & 3) * 16384;
#pragma unroll
                for (int i = 0; i < 8; ++i) {
                    const int k = wave * 256 + i * 32;
#pragma unroll
                    for (int m = 0; m < 4; ++m) {
                        f16x8 a = ld_tile(hprev, k, m, kg, r);
                        acc[m] = __builtin_amdgcn_mfma_f32_16x16x32_f16(a, w0h[i], acc[m], 0, 0, 0);
                    }
                }
            }
        } else {
            // ===== layer 1, step t : A = [h0(t) | h1(t-1)] =====
            // --- phase A: own-chain h1(t-1) first (usually ready earlier)
            if (t >= 1) {
                wave_wait(myslice_L1, (unsigned)t, nullptr, 0u);
                const u64* h1prev = h1buf + (size_t)((t - 1) & 3) * 16384;
#pragma unroll
                for (int i = 0; i < 8; ++i) {
                    const int k = wave * 256 + i * 32;
#pragma unroll
                    for (int m = 0; m < 4; ++m) {
                        f16x8 a = ld_tile(h1prev, k, m, kg, r);
                        acc[m] = __builtin_amdgcn_mfma_f32_16x16x32_f16(a, w1b[i], acc[m], 0, 0, 0);
                    }
                }
            }
            // --- phase B: h0(t) from L0 chain
            wave_wait(myslice_L0, (unsigned)(t + 1), nullptr, 0u);
            const u64* h0cur = hbuf0 + (size_t)(t & 3) * 16384;
#pragma unroll
            for (int i = 0; i < 8; ++i) {
                const int k = wave * 256 + i * 32;
#pragma unroll
                for (int m = 0; m < 4; ++m) {
                    f16x8 a = ld_tile(h0cur, k, m, kg, r);
                    acc[m] = __builtin_amdgcn_mfma_f32_16x16x32_f16(a, w1a[i], acc[m], 0, 0, 0);
                }
            }
        }

        // ---------- cross-wave reduce + epilogue ----------
#pragma unroll
        for (int m = 0; m < 4; ++m)
#pragma unroll
            for (int rr = 0; rr < 4; ++rr)
                red[wave][m * 16 + kg * 4 + rr][r] = acc[m][rr];
        __syncthreads();
        {
            const int row = tid >> 2;          // 0..63
            const int c   = (tid & 3) * 4;     // 0,4,8,12
            f32x4 s = *reinterpret_cast<f32x4*>(&red[0][row][c]);
#pragma unroll
            for (int w = 1; w < 4; ++w) s += *reinterpret_cast<f32x4*>(&red[w][row][c]);
            const int nb = tile * 16 + c;
            const float* bp = bias + (isL1 ? 1024 : 0) + (dir ? 2048 : 0) + nb;
            float4 bv = *reinterpret_cast<const float4*>(bp);
            float v0 = tanhf(s[0] + bv.x), v1 = tanhf(s[1] + bv.y);
            float v2 = tanhf(s[2] + bv.z), v3 = tanhf(s[3] + bv.w);
            f16x4 hv; hv[0] = (_Float16)v0; hv[1] = (_Float16)v1;
            hv[2] = (_Float16)v2; hv[3] = (_Float16)v3;
            u64* hout = (isL1 ? h1buf : hbuf0) + (size_t)(t & 3) * 16384;
            st_tile(hout, row, nb, hv);
            if (isL1 && t == SS - 1) {
                float4 fv; fv.x = v0; fv.y = v1; fv.z = v2; fv.w = v3;
                *reinterpret_cast<float4*>(h1fin + (size_t)dir * (BB * HH) + row * HH + nb) = fv;
            }
        }
        // ---------- publish: drain all waves' sc1 stores, then flag = t+1 (plain store)
        __syncthreads();
        if (tid == 0)
            __hip_atomic_store(F_own, (unsigned)(t + 1), __ATOMIC_RELAXED,
                               __HIP_MEMORY_SCOPE_AGENT);
    }
}

// ---------- FC head (all fp32, runs once) ----------
__global__ void fc1_kernel(const float* __restrict__ h1fin, const float* __restrict__ w,
                           const float* __restrict__ b, float* __restrict__ v)
{
    int idx = blockIdx.x * 256 + threadIdx.x;   // (batch, out-feature)
    int bb = idx >> 6, nn = idx & 63;
    const float* hf = h1fin + bb * HH;
    const float* hb = h1fin + BB * HH + bb * HH;
    float s = b[nn];
#pragma unroll 8
    for (int k = 0; k < HH; ++k) s += hf[k] * w[k * 64 + nn];
#pragma unroll 8
    for (int k = 0; k < HH; ++k) s += hb[k] * w[(HH + k) * 64 + nn];
    v[idx] = s;
}

__global__ void fc2_kernel(const float* __restrict__ v, const float* __restrict__ w,
                           const float* __restrict__ b, float* __restrict__ out)
{
    int idx = threadIdx.x;
    if (idx >= BB * 2) return;
    int bb = idx >> 1, c = idx & 1;
    float s = b[c];
    const float* vb = v + bb * 64;
#pragma unroll
    for (int j = 0; j < 64; ++j) s += vb[j] * w[j * 2 + c];
    out[bb * 2 + c] = s;
}

extern "C" void kernel_launch(void* const* d_in, const int* in_sizes, int n_in,
                              void* d_out, int out_size, void* d_ws, size_t ws_size,
                              hipStream_t stream)
{
    const int*   x        = (const int*)  d_in[0];
    const float* emb      = (const float*)d_in[1];
    const float* fw0_wih  = (const float*)d_in[2];
    const float* fw0_bih  = (const float*)d_in[3];
    const float* fw0_whh  = (const float*)d_in[4];
    const float* fw0_bhh  = (const float*)d_in[5];
    const float* fw1_wih  = (const float*)d_in[6];
    const float* fw1_bih  = (const float*)d_in[7];
    const float* fw1_whh  = (const float*)d_in[8];
    const float* fw1_bhh  = (const float*)d_in[9];
    const float* bw0_wih  = (const float*)d_in[10];
    const float* bw0_bih  = (const float*)d_in[11];
    const float* bw0_whh  = (const float*)d_in[12];
    const float* bw0_bhh  = (const float*)d_in[13];
    const float* bw1_wih  = (const float*)d_in[14];
    const float* bw1_bih  = (const float*)d_in[15];
    const float* bw1_whh  = (const float*)d_in[16];
    const float* bw1_bhh  = (const float*)d_in[17];
    const float* fc1_w    = (const float*)d_in[18];
    const float* fc1_b    = (const float*)d_in[19];
    const float* fc2_w    = (const float*)d_in[20];
    const float* fc2_b    = (const float*)d_in[21];

    size_t off = 0;
    char* wsb = (char*)d_ws;
    auto take = [&](size_t bytes) -> void* {
        void* p = wsb + off;
        off += (bytes + 255) & ~(size_t)255;
        return p;
    };
    _Float16* W0f   = (_Float16*)take((size_t)HH * 1536 * 2);
    _Float16* W1f   = (_Float16*)take((size_t)HH * 2048 * 2);
    _Float16* W0b   = (_Float16*)take((size_t)HH * 1536 * 2);
    _Float16* W1b   = (_Float16*)take((size_t)HH * 2048 * 2);
    float*    bias  = (float*)   take(4096 * 4);
    u64*      h0f   = (u64*)     take((size_t)4 * 16384 * 8);
    u64*      h1f   = (u64*)     take((size_t)4 * 16384 * 8);
    u64*      h0b   = (u64*)     take((size_t)4 * 16384 * 8);
    u64*      h1b   = (u64*)     take((size_t)4 * 16384 * 8);
    float*    h1fin = (float*)   take((size_t)2 * BB * HH * 4);
    float*    vmid  = (float*)   take(4096 * 4);
    unsigned* flg   = (unsigned*)take((size_t)4 * 64 * 16 * 4);   // 4 chains x 64 blocks x 64B
    _Float16* embx  = (_Float16*)take((size_t)SS * BB * EE * 2);  // 32 MB
    bool use_embx = (ws_size >= off);

    prep_wt<<<1536, 256, 0, stream>>>(fw0_wih, fw0_whh, EE, 1536, W0f);
    prep_wt<<<2048, 256, 0, stream>>>(fw1_wih, fw1_whh, HH, 2048, W1f);
    prep_wt<<<1536, 256, 0, stream>>>(bw0_wih, bw0_whh, EE, 1536, W0b);
    prep_wt<<<2048, 256, 0, stream>>>(bw1_wih, bw1_whh, HH, 2048, W1b);
    prep_bias<<<1, 1024, 0, stream>>>(fw0_bih, fw0_bhh, fw1_bih, fw1_bhh,
                                      bw0_bih, bw0_bhh, bw1_bih, bw1_bhh, bias);
    if (use_embx)
        prep_embx<<<SS * BB, 128, 0, stream>>>(x, emb, embx);
    hipMemsetAsync(flg, 0, (size_t)4 * 64 * 16 * 4, stream);

    const _Float16* embx_arg = use_embx ? embx : nullptr;
    void* args[] = {(void*)&x, (void*)&emb, (void*)&embx_arg,
                    (void*)&W0f, (void*)&W1f, (void*)&W0b, (void*)&W1b,
                    (void*)&bias, (void*)&h0f, (void*)&h1f, (void*)&h0b, (void*)&h1b,
                    (void*)&h1fin, (void*)&flg};
    hipLaunchCooperativeKernel((void*)rnn_persistent, dim3(256), dim3(256), args, 0, stream);

    fc1_kernel<<<16, 256, 0, stream>>>(h1fin, fc1_w, fc1_b, vmid);
    fc2_kernel<<<1, 128, 0, stream>>>(vmid, fc2_w, fc2_b, (float*)d_out);
}